// Round 5
// baseline (211.129 us; speedup 1.0000x reference)
//
#include <hip/hip_runtime.h>
#include <stdint.h>

#pragma clang fp contract(off)

#define NUM_CLASSES 81
#define TOP_K 200
#define BATCH 32
#define NUM_PRIORS 16384
#define CAP 512
#define CONF_T 0.01f
#define NMS_T 0.45f
#define PIVOT_S 0.97827148f
#define NTASK (BATCH * (NUM_CLASSES - 1))
#define QCAP 1536               // LDS queue depth (mean ~450, 50 sigma headroom)
#define FILTER_BLOCKS 2048      // 64 blocks per image, 256 prior-rows per block

typedef unsigned long long u64;
typedef unsigned int u32;

// Correctly-rounded f32 exp via f64 — verified bit-compatible R0-R3 (absmax 3e-8).
__device__ __forceinline__ float exp_ref(float x) {
#pragma clang fp contract(off)
    return (float)exp((double)x);
}

struct SharedBlk {
    u64 keys[CAP];          // gathered candidate keys (bits(score)<<32 | ~p)
    u64 sup[TOP_K][4];      // suppression bitmask rows (bits k>j with iou>thr)
    float box[TOP_K][5];    // x1,y1,x2,y2,area — 20B stride: gcd(5,32)=1 -> conflict-free
    float score[TOP_K];
    u64 keep[4];
    u32 acc;                // count accumulator
    u32 ctr;                // gather append counter
};

// Count elements with key > pivot (valid = score > CONF_T; invalid key == 0).
__device__ int count_pass(const float* cbase, u64 pivot, int tid, int lane, u32* s_acc) {
#pragma clang fp contract(off)
    __syncthreads();
    if (tid == 0) *s_acc = 0u;
    __syncthreads();
    u32 ph = (u32)(pivot >> 32), pl = (u32)pivot;
    u32 c = 0;
    for (int j = 0; j < 64; ++j) {
        int p = tid + (j << 8);
        float s = cbase[(size_t)p * NUM_CLASSES];
        bool valid = s > CONF_T;
        u32 bt = valid ? __float_as_uint(s) : 0u;
        u32 il = ~(u32)p;
        c += (valid && ((bt > ph) || ((bt == ph) && (il > pl)))) ? 1u : 0u;
    }
    for (int off = 32; off > 0; off >>= 1) c += __shfl_down(c, off, 64);
    if (lane == 0) atomicAdd(s_acc, c);
    __syncthreads();
    return (int)*s_acc;
}

// Count AND gather (capped at CAP) elements with key > pivot into s_keys.
__device__ int gather_pass(const float* cbase, u64 pivot, int tid, int lane,
                           u64* s_keys, u32* s_acc, u32* s_ctr) {
#pragma clang fp contract(off)
    __syncthreads();
    if (tid == 0) { *s_acc = 0u; *s_ctr = 0u; }
    for (int q = tid; q < CAP; q += 256) s_keys[q] = 0ull;
    __syncthreads();
    u32 ph = (u32)(pivot >> 32), pl = (u32)pivot;
    u32 cnt = 0;
    for (int j = 0; j < 64; ++j) {
        int p = tid + (j << 8);
        float s = cbase[(size_t)p * NUM_CLASSES];
        bool valid = s > CONF_T;
        u32 bt = valid ? __float_as_uint(s) : 0u;
        u32 il = ~(u32)p;
        bool pred = valid && ((bt > ph) || ((bt == ph) && (il > pl)));
        cnt += pred ? 1u : 0u;
        u64 mk = __ballot(pred);
        u32 off = 0;
        if (lane == 0 && mk) off = atomicAdd(s_ctr, (u32)__popcll(mk));
        off = __shfl(off, 0, 64);
        if (pred) {
            u32 pos = off + (u32)__popcll(mk & ((1ull << lane) - 1ull));
            if (pos < CAP) s_keys[pos] = ((u64)bt << 32) | il;
        }
    }
    for (int off2 = 32; off2 > 0; off2 >>= 1) cnt += __shfl_down(cnt, off2, 64);
    if (lane == 0) atomicAdd(s_acc, cnt);
    __syncthreads();
    return (int)*s_acc;
}

// ---- Kernel 1: coalesced filter, LDS-staged, max-MLP.
// All 20 full-group loads issued back-to-back (plus 1 predicated tail load)
// before any processing: ~21 outstanding 16B loads/thread hides HBM latency.
// Flush phase does XCD-local global atomics (img = bid&31 -> bid%8 fixed XCD).
__global__ __launch_bounds__(256) void filter_kernel(
    const float4* __restrict__ conf4,
    u32* __restrict__ counts, u64* __restrict__ keys)
{
#pragma clang fp contract(off)
    __shared__ u64 qkey[QCAP];
    __shared__ u32 qtask[QCAP];
    __shared__ u32 qn;

    const int tid = threadIdx.x;
    const int bid = blockIdx.x;
    const int img = bid & 31;        // all blocks of an image share one XCD (bid%8 fixed)
    const int chunk = bid >> 5;      // 64 chunks x 256 prior-rows
    const int row0 = img * NUM_PRIORS + chunk * 256;
    const int base4 = row0 * NUM_CLASSES / 4;   // row0 multiple of 256 -> divisible by 4

    if (tid == 0) qn = 0u;
    __syncthreads();

    // 256 rows x 81 classes = 5184 float4 = 20*256 + 64.
    // Issue ALL loads first (independent addresses -> back-to-back vmcnt queue).
    float4 v[20];
    #pragma unroll
    for (int g = 0; g < 20; ++g)
        v[g] = conf4[base4 + tid + g * 256];
    float4 vt;
    if (tid < 64) vt = conf4[base4 + tid + 20 * 256];   // exec-masked tail load

    #pragma unroll
    for (int g = 0; g < 20; ++g) {
        int le4 = tid + g * 256;
        float vv[4] = {v[g].x, v[g].y, v[g].z, v[g].w};
        #pragma unroll
        for (int j = 0; j < 4; ++j) {
            float s = vv[j];
            if (s > PIVOT_S) {                       // P ~= 2.2% per element
                u32 pos = atomicAdd(&qn, 1u);        // LDS atomic, rare
                int le = le4 * 4 + j;
                u32 lrow = (u32)le / NUM_CLASSES;    // magic-mul
                u32 c = (u32)le - lrow * NUM_CLASSES;
                if (pos < QCAP) {
                    u32 p = (u32)(chunk * 256) + lrow;
                    qkey[pos] = ((u64)__float_as_uint(s) << 32) | (u32)(~p);
                    qtask[pos] = (c != 0) ? (u32)(img * 80 + (int)c - 1) : 0xFFFFFFFFu;
                }
            }
        }
    }
    if (tid < 64) {
        int le4 = tid + 20 * 256;
        float vv[4] = {vt.x, vt.y, vt.z, vt.w};
        #pragma unroll
        for (int j = 0; j < 4; ++j) {
            float s = vv[j];
            if (s > PIVOT_S) {
                u32 pos = atomicAdd(&qn, 1u);
                int le = le4 * 4 + j;
                u32 lrow = (u32)le / NUM_CLASSES;
                u32 c = (u32)le - lrow * NUM_CLASSES;
                if (pos < QCAP) {
                    u32 p = (u32)(chunk * 256) + lrow;
                    qkey[pos] = ((u64)__float_as_uint(s) << 32) | (u32)(~p);
                    qtask[pos] = (c != 0) ? (u32)(img * 80 + (int)c - 1) : 0xFFFFFFFFu;
                }
            }
        }
    }
    __syncthreads();

    u32 qtotal = qn;
    u32 qvalid = qtotal < QCAP ? qtotal : QCAP;
    // flush: global atomics, all to this image's counters (XCD-local L2)
    for (u32 q = tid; q < qvalid; q += 256) {
        u32 t = qtask[q];
        if (t != 0xFFFFFFFFu) {
            u32 slot = atomicAdd(&counts[t], 1u);
            if (slot < CAP) keys[(size_t)t * CAP + slot] = qkey[q];
        }
    }
    if (qtotal > QCAP) {
        // ~50-sigma event: poison this image's counts -> nms exact fallback
        if (tid < 80) atomicAdd(&counts[img * 80 + tid], 0x01000000u);
    }
}

// ---- Kernel 2: per-(img,class) sort + NMS. Fast path reads keys from ws;
// exact fallback (count outside [TOP_K, CAP]) re-scans the conf column.
__global__ __launch_bounds__(256) void nms_kernel(
    const float* __restrict__ loc_data,   // [B,P,4]
    const float* __restrict__ conf_data,  // [B*P,C]
    const float* __restrict__ prior_data, // [P,4]
    const u32* __restrict__ counts,       // [NTASK] (may be null)
    const u64* __restrict__ gkeys,        // [NTASK][CAP] (may be null)
    float* __restrict__ out,              // [B,C,K,5], pre-zeroed
    int use_ws)
{
#pragma clang fp contract(off)
    __shared__ SharedBlk sh;
    const int tid = threadIdx.x;
    const int lane = tid & 63;
    const int wv = tid >> 6;
    const int b = blockIdx.x;
    const int img = b / 80;
    const int r = b - img * 80;
    const int cl = r + 1;
    const int task = img * 80 + r;

    const float* cbase = conf_data + (size_t)img * NUM_PRIORS * NUM_CLASSES + cl;

    // ---- Phase 1: candidate set (ws fast path, else exact strided fallback)
    int m = -1;
    if (use_ws) {
        u32 cnt = counts[task];
        if (cnt >= TOP_K && cnt <= CAP) {
            const u64* src = gkeys + (size_t)task * CAP;
            for (int q = tid; q < CAP; q += 256)
                sh.keys[q] = (q < (int)cnt) ? src[q] : 0ull;
            m = (int)cnt;
        }
    }
    if (m < 0) {
        u64 pivot = ((u64)__float_as_uint(PIVOT_S) << 32) | 0xFFFFFFFFull;
        m = gather_pass(cbase, pivot, tid, lane, sh.keys, &sh.acc, &sh.ctr);
        if (m < TOP_K || m > CAP) {
            const u32 B001 = __float_as_uint(CONF_T);
            int nvalid = count_pass(cbase, ((u64)B001 << 32) | 0xFFFFFFFFull, tid, lane, &sh.acc);
            if (nvalid <= CAP) {
                pivot = 0ull;  // gather all valid
            } else {
                u64 lo = ((u64)B001 << 32) | 0xFFFFFFFFull;
                u64 hi = ~0ull;
                for (int it = 0; it < 64; ++it) {
                    u64 mid = lo + ((hi - lo) >> 1);
                    int c = count_pass(cbase, mid, tid, lane, &sh.acc);
                    if (c >= TOP_K && c <= CAP) { pivot = mid; break; }
                    if (c > CAP) lo = mid; else hi = mid;
                }
            }
            m = gather_pass(cbase, pivot, tid, lane, sh.keys, &sh.acc, &sh.ctr);
        }
    }
    const int nk = m < TOP_K ? m : TOP_K;

    // ---- Phase 2: bitonic sort CAP keys descending (keys distinct)
    for (int k2 = 2; k2 <= CAP; k2 <<= 1) {
        for (int jj = k2 >> 1; jj > 0; jj >>= 1) {
            __syncthreads();
            for (int i = tid; i < CAP; i += 256) {
                int ixj = i ^ jj;
                if (ixj > i) {
                    u64 a = sh.keys[i], bb = sh.keys[ixj];
                    bool up = ((i & k2) == 0);
                    if (up ? (a < bb) : (a > bb)) { sh.keys[i] = bb; sh.keys[ixj] = a; }
                }
            }
        }
    }
    __syncthreads();

    // ---- Phase 3: decode candidate boxes (reference op order)
    if (tid < nk) {
        u64 key = sh.keys[tid];
        int p = (int)(~(u32)key);
        float sc = __uint_as_float((u32)(key >> 32));
        const float4 lc = *(const float4*)(loc_data + ((size_t)img * NUM_PRIORS + p) * 4);
        const float4 pr = *(const float4*)(prior_data + (size_t)p * 4);
        float cx = pr.x + (lc.x * 0.1f) * pr.z;
        float cy = pr.y + (lc.y * 0.1f) * pr.w;
        float w  = pr.z * exp_ref(lc.z * 0.2f);
        float h  = pr.w * exp_ref(lc.w * 0.2f);
        float x1 = cx - 0.5f * w;
        float y1 = cy - 0.5f * h;
        float x2 = x1 + w;
        float y2 = y1 + h;
        sh.box[tid][0] = x1; sh.box[tid][1] = y1; sh.box[tid][2] = x2; sh.box[tid][3] = y2;
        sh.box[tid][4] = fmaxf(x2 - x1, 0.0f) * fmaxf(y2 - y1, 0.0f);
        sh.score[tid] = sc;
    }
    __syncthreads();

    // ---- Phase 4: row-per-thread suppression masks (upper triangle, regs only)
    {
        u64 m0 = 0ull, m1 = 0ull, m2 = 0ull, m3 = 0ull;
        if (tid < nk) {
            const float bx0 = sh.box[tid][0], by0 = sh.box[tid][1];
            const float bx1 = sh.box[tid][2], by1 = sh.box[tid][3];
            const float aj  = sh.box[tid][4];
            #pragma unroll
            for (int c = 0; c < 4; ++c) {
                u64 mm = 0ull;
                int klo = tid + 1 > (c << 6) ? tid + 1 : (c << 6);
                int khi = nk < ((c + 1) << 6) ? nk : ((c + 1) << 6);
                for (int k = klo; k < khi; ++k) {
                    float ltx = fmaxf(bx0, sh.box[k][0]);
                    float lty = fmaxf(by0, sh.box[k][1]);
                    float rbx = fminf(bx1, sh.box[k][2]);
                    float rby = fminf(by1, sh.box[k][3]);
                    float wx = fmaxf(rbx - ltx, 0.0f);
                    float wy = fmaxf(rby - lty, 0.0f);
                    float inter = wx * wy;
                    float uni = (aj + sh.box[k][4]) - inter;
                    float iou = inter / fmaxf(uni, 1e-12f);
                    if (iou > NMS_T) mm |= 1ull << (k & 63);
                }
                if (c == 0) m0 = mm; else if (c == 1) m1 = mm;
                else if (c == 2) m2 = mm; else m3 = mm;
            }
        }
        if (tid < TOP_K) {
            sh.sup[tid][0] = m0; sh.sup[tid][1] = m1;
            sh.sup[tid][2] = m2; sh.sup[tid][3] = m3;
        }
    }
    __syncthreads();

    // ---- Phase 5: greedy resolve on wave 0 (64-bit chunks, shfl broadcast)
    if (wv == 0) {
        u64 kws[4];
        #pragma unroll
        for (int w = 0; w < 4; ++w) {
            int rem = nk - (w << 6);
            kws[w] = rem >= 64 ? ~0ull : (rem <= 0 ? 0ull : ((1ull << rem) - 1ull));
        }
        for (int c = 0; c < 4; ++c) {
            int row = (c << 6) + lane;
            u64 myrow = (row < TOP_K) ? sh.sup[row][c] : 0ull;
            u64 kw = kws[c];
            u64 nz = __ballot(myrow != 0ull);
            u64 t = kw & nz;
            while (t) {
                int j = __ffsll(t) - 1;
                u64 rj = __shfl(myrow, j, 64);
                kw &= ~rj;
                t &= ~(1ull << j);
                t &= kw;
            }
            kws[c] = kw;
            for (int w2 = c + 1; w2 < 4; ++w2) {
                u64 contrib = (row < TOP_K && ((kw >> lane) & 1ull)) ? sh.sup[row][w2] : 0ull;
                #pragma unroll
                for (int off = 32; off > 0; off >>= 1) contrib |= __shfl_xor(contrib, off, 64);
                kws[w2] &= ~contrib;
            }
        }
        if (lane == 0) {
            sh.keep[0] = kws[0]; sh.keep[1] = kws[1];
            sh.keep[2] = kws[2]; sh.keep[3] = kws[3];
        }
    }
    __syncthreads();

    // ---- Phase 6: stable compaction of kept rows
    if (tid < nk) {
        int w = tid >> 6, rr = tid & 63;
        u64 kwv = sh.keep[w];
        if ((kwv >> rr) & 1ull) {
            int pos = __popcll(kwv & ((1ull << rr) - 1ull));
            for (int q = 0; q < w; ++q) pos += __popcll(sh.keep[q]);
            float* o = out + (((size_t)img * NUM_CLASSES + cl) * TOP_K + pos) * 5;
            o[0] = sh.score[tid];
            o[1] = sh.box[tid][0];
            o[2] = sh.box[tid][1];
            o[3] = sh.box[tid][2];
            o[4] = sh.box[tid][3];
        }
    }
}

extern "C" void kernel_launch(void* const* d_in, const int* in_sizes, int n_in,
                              void* d_out, int out_size, void* d_ws, size_t ws_size,
                              hipStream_t stream) {
    const float* loc   = (const float*)d_in[0];
    const float* conf  = (const float*)d_in[1];
    const float* prior = (const float*)d_in[2];
    float* out = (float*)d_out;

    hipMemsetAsync(d_out, 0, (size_t)out_size * sizeof(float), stream);

    // ws layout: [0, NTASK*4) counts | [65536, 65536 + NTASK*CAP*8) keys
    const size_t need = 65536 + (size_t)NTASK * CAP * 8;
    const int use_ws = (ws_size >= need) ? 1 : 0;   // constant per session -> deterministic

    u32* counts = (u32*)d_ws;
    u64* keys   = (u64*)((char*)d_ws + 65536);

    if (use_ws) {
        hipMemsetAsync(d_ws, 0, NTASK * sizeof(u32), stream);
        filter_kernel<<<FILTER_BLOCKS, 256, 0, stream>>>((const float4*)conf, counts, keys);
    }
    nms_kernel<<<NTASK, 256, 0, stream>>>(loc, conf, prior,
                                          use_ws ? counts : nullptr,
                                          use_ws ? keys : nullptr,
                                          out, use_ws);
}

// Round 6
// 205.387 us; speedup vs baseline: 1.0280x; 1.0280x over previous
//
#include <hip/hip_runtime.h>
#include <stdint.h>

#pragma clang fp contract(off)

#define NUM_CLASSES 81
#define TOP_K 200
#define BATCH 32
#define NUM_PRIORS 16384
#define CAP 512
#define CONF_T 0.01f
#define NMS_T 0.45f
#define PIVOT_S 0.97827148f
#define NTASK (BATCH * (NUM_CLASSES - 1))
#define QCAP 768                // mean ~222 hits/block, +36 sigma headroom
#define ROWS_PER_BLK 128
#define FILTER_BLOCKS 4096      // 128 chunks x 32 images

typedef unsigned long long u64;
typedef unsigned int u32;

// Correctly-rounded f32 exp via f64 — verified bit-compatible R0-R4 (absmax 3e-8).
__device__ __forceinline__ float exp_ref(float x) {
#pragma clang fp contract(off)
    return (float)exp((double)x);
}

struct SharedBlk {
    u64 keys[CAP];          // canonical keys: bits(score)<<32 | (u32)(~p)
    u64 sup[TOP_K][4];      // suppression bitmask rows (bits k>j with iou>thr)
    float box[TOP_K][5];    // x1,y1,x2,y2,area — 20B stride: gcd(5,32)=1 -> conflict-free
    float score[TOP_K];
    u64 keep[4];
    u32 acc;                // count accumulator
    u32 ctr;                // gather append counter
};

// Count elements with key > pivot (valid = score > CONF_T; invalid key == 0).
__device__ int count_pass(const float* cbase, u64 pivot, int tid, int lane, u32* s_acc) {
#pragma clang fp contract(off)
    __syncthreads();
    if (tid == 0) *s_acc = 0u;
    __syncthreads();
    u32 ph = (u32)(pivot >> 32), pl = (u32)pivot;
    u32 c = 0;
    for (int j = 0; j < 64; ++j) {
        int p = tid + (j << 8);
        float s = cbase[(size_t)p * NUM_CLASSES];
        bool valid = s > CONF_T;
        u32 bt = valid ? __float_as_uint(s) : 0u;
        u32 il = ~(u32)p;
        c += (valid && ((bt > ph) || ((bt == ph) && (il > pl)))) ? 1u : 0u;
    }
    for (int off = 32; off > 0; off >>= 1) c += __shfl_down(c, off, 64);
    if (lane == 0) atomicAdd(s_acc, c);
    __syncthreads();
    return (int)*s_acc;
}

// Count AND gather (capped at CAP) elements with key > pivot into s_keys.
__device__ int gather_pass(const float* cbase, u64 pivot, int tid, int lane,
                           u64* s_keys, u32* s_acc, u32* s_ctr) {
#pragma clang fp contract(off)
    __syncthreads();
    if (tid == 0) { *s_acc = 0u; *s_ctr = 0u; }
    for (int q = tid; q < CAP; q += 256) s_keys[q] = 0ull;
    __syncthreads();
    u32 ph = (u32)(pivot >> 32), pl = (u32)pivot;
    u32 cnt = 0;
    for (int j = 0; j < 64; ++j) {
        int p = tid + (j << 8);
        float s = cbase[(size_t)p * NUM_CLASSES];
        bool valid = s > CONF_T;
        u32 bt = valid ? __float_as_uint(s) : 0u;
        u32 il = ~(u32)p;
        bool pred = valid && ((bt > ph) || ((bt == ph) && (il > pl)));
        cnt += pred ? 1u : 0u;
        u64 mk = __ballot(pred);
        u32 off = 0;
        if (lane == 0 && mk) off = atomicAdd(s_ctr, (u32)__popcll(mk));
        off = __shfl(off, 0, 64);
        if (pred) {
            u32 pos = off + (u32)__popcll(mk & ((1ull << lane) - 1ull));
            if (pos < CAP) s_keys[pos] = ((u64)bt << 32) | il;
        }
    }
    for (int off2 = 32; off2 > 0; off2 >>= 1) cnt += __shfl_down(cnt, off2, 64);
    if (lane == 0) atomicAdd(s_acc, cnt);
    __syncthreads();
    return (int)*s_acc;
}

// ---- Kernel 1: coalesced filter, LDS-staged, ballot-aggregated.
// Streaming loop: prefetch depth 10, one lane-0 LDS atomic per hit-group
// (no per-lane atomic->store latency chains). Flush: XCD-local global atomics
// (img = bid&31 -> bid%8 = fixed XCD).
__global__ __launch_bounds__(256) void filter_kernel(
    const float4* __restrict__ conf4,
    u32* __restrict__ counts, u64* __restrict__ keys)
{
#pragma clang fp contract(off)
    __shared__ u64 qkey[QCAP];
    __shared__ u32 qn;

    const int tid = threadIdx.x;
    const int lane = tid & 63;
    const int bid = blockIdx.x;
    const int img = bid & 31;        // image pinned to one XCD (bid%8 fixed)
    const int chunk = bid >> 5;      // 128 chunks x 128 prior-rows
    const int row0 = img * NUM_PRIORS + chunk * ROWS_PER_BLK;
    const int base4 = row0 * NUM_CLASSES / 4;   // 128*81 = 10368 elems = 2592 float4

    if (tid == 0) qn = 0u;
    __syncthreads();

    // 2592 float4 = 10*256 + 32: issue all 10 full-group loads, then tail.
    float4 v[10];
    #pragma unroll
    for (int g = 0; g < 10; ++g)
        v[g] = conf4[base4 + tid + g * 256];
    float4 vt;
    if (tid < 32) vt = conf4[base4 + tid + 2560];

    #pragma unroll
    for (int g = 0; g < 11; ++g) {
        if (g == 10 && tid >= 32) {
            // keep wave shape: lanes without tail data just carry hit=false
        }
        float vv[4];
        if (g < 10) { vv[0] = v[g].x; vv[1] = v[g].y; vv[2] = v[g].z; vv[3] = v[g].w; }
        else        { vv[0] = vt.x;  vv[1] = vt.y;  vv[2] = vt.z;  vv[3] = vt.w; }
        int le4 = tid + g * 256;
        bool in_range = (g < 10) || (tid < 32);
        #pragma unroll
        for (int j = 0; j < 4; ++j) {
            bool hit = false;
            u64 key = 0ull;
            if (in_range && vv[j] > PIVOT_S) {       // rare (~2.2%/elem)
                int le = le4 * 4 + j;
                u32 lrow = (u32)le / NUM_CLASSES;    // magic-mul
                u32 c = (u32)le - lrow * NUM_CLASSES;
                if (c != 0) {
                    u32 p = (u32)(chunk * ROWS_PER_BLK) + lrow;   // prior idx in image
                    key = ((u64)__float_as_uint(vv[j]) << 32)
                        | ((u64)(16383u - p) << 7) | (u64)(c - 1u);
                    hit = true;
                }
            }
            u64 mk = __ballot(hit);
            if (mk) {
                u32 base = 0;
                if (lane == 0) base = atomicAdd(&qn, (u32)__popcll(mk));
                base = __shfl(base, 0, 64);
                if (hit) {
                    u32 pos = base + (u32)__popcll(mk & ((1ull << lane) - 1ull));
                    if (pos < QCAP) qkey[pos] = key;
                }
            }
        }
    }
    __syncthreads();

    u32 qtotal = qn;
    u32 qvalid = qtotal < QCAP ? qtotal : QCAP;
    // flush: global atomics, all to this image's counters (XCD-local L2)
    for (u32 q = tid; q < qvalid; q += 256) {
        u64 k = qkey[q];
        u32 t = (u32)img * 80u + (u32)(k & 0x7Full);
        u32 slot = atomicAdd(&counts[t], 1u);
        if (slot < CAP) keys[(size_t)t * CAP + slot] = k;
    }
    if (qtotal > QCAP) {
        // ~36-sigma event: poison this image's counts -> nms exact fallback
        if (tid < 80) atomicAdd(&counts[img * 80 + tid], 0x01000000u);
    }
}

// ---- Kernel 2: per-(img,class) sort + NMS. Fast path reads keys from ws;
// exact fallback (count outside [TOP_K, CAP]) re-scans the conf column.
__global__ __launch_bounds__(256) void nms_kernel(
    const float* __restrict__ loc_data,   // [B,P,4]
    const float* __restrict__ conf_data,  // [B*P,C]
    const float* __restrict__ prior_data, // [P,4]
    const u32* __restrict__ counts,       // [NTASK] (may be null)
    const u64* __restrict__ gkeys,        // [NTASK][CAP] (may be null)
    float* __restrict__ out,              // [B,C,K,5], pre-zeroed
    int use_ws)
{
#pragma clang fp contract(off)
    __shared__ SharedBlk sh;
    const int tid = threadIdx.x;
    const int lane = tid & 63;
    const int wv = tid >> 6;
    const int b = blockIdx.x;
    const int img = b / 80;
    const int r = b - img * 80;
    const int cl = r + 1;
    const int task = img * 80 + r;

    const float* cbase = conf_data + (size_t)img * NUM_PRIORS * NUM_CLASSES + cl;

    // ---- Phase 1: candidate set (ws fast path, else exact strided fallback)
    int m = -1;
    if (use_ws) {
        u32 cnt = counts[task];
        if (cnt >= TOP_K && cnt <= CAP) {
            const u64* src = gkeys + (size_t)task * CAP;
            for (int q = tid; q < CAP; q += 256) {
                u64 k = 0ull;
                if (q < (int)cnt) {
                    u64 kw = src[q];
                    u32 p = 16383u - ((u32)(kw >> 7) & 0x3FFFu);
                    k = (kw & 0xFFFFFFFF00000000ull) | (u64)(u32)(~p);
                }
                sh.keys[q] = k;
            }
            m = (int)cnt;
        }
    }
    if (m < 0) {
        u64 pivot = ((u64)__float_as_uint(PIVOT_S) << 32) | 0xFFFFFFFFull;
        m = gather_pass(cbase, pivot, tid, lane, sh.keys, &sh.acc, &sh.ctr);
        if (m < TOP_K || m > CAP) {
            const u32 B001 = __float_as_uint(CONF_T);
            int nvalid = count_pass(cbase, ((u64)B001 << 32) | 0xFFFFFFFFull, tid, lane, &sh.acc);
            if (nvalid <= CAP) {
                pivot = 0ull;  // gather all valid
            } else {
                u64 lo = ((u64)B001 << 32) | 0xFFFFFFFFull;
                u64 hi = ~0ull;
                for (int it = 0; it < 64; ++it) {
                    u64 mid = lo + ((hi - lo) >> 1);
                    int c = count_pass(cbase, mid, tid, lane, &sh.acc);
                    if (c >= TOP_K && c <= CAP) { pivot = mid; break; }
                    if (c > CAP) lo = mid; else hi = mid;
                }
            }
            m = gather_pass(cbase, pivot, tid, lane, sh.keys, &sh.acc, &sh.ctr);
        }
    }
    const int nk = m < TOP_K ? m : TOP_K;

    // ---- Phase 2: bitonic sort CAP keys descending (keys distinct)
    for (int k2 = 2; k2 <= CAP; k2 <<= 1) {
        for (int jj = k2 >> 1; jj > 0; jj >>= 1) {
            __syncthreads();
            for (int i = tid; i < CAP; i += 256) {
                int ixj = i ^ jj;
                if (ixj > i) {
                    u64 a = sh.keys[i], bb = sh.keys[ixj];
                    bool up = ((i & k2) == 0);
                    if (up ? (a < bb) : (a > bb)) { sh.keys[i] = bb; sh.keys[ixj] = a; }
                }
            }
        }
    }
    __syncthreads();

    // ---- Phase 3: decode candidate boxes (reference op order)
    if (tid < nk) {
        u64 key = sh.keys[tid];
        int p = (int)(~(u32)key);
        float sc = __uint_as_float((u32)(key >> 32));
        const float4 lc = *(const float4*)(loc_data + ((size_t)img * NUM_PRIORS + p) * 4);
        const float4 pr = *(const float4*)(prior_data + (size_t)p * 4);
        float cx = pr.x + (lc.x * 0.1f) * pr.z;
        float cy = pr.y + (lc.y * 0.1f) * pr.w;
        float w  = pr.z * exp_ref(lc.z * 0.2f);
        float h  = pr.w * exp_ref(lc.w * 0.2f);
        float x1 = cx - 0.5f * w;
        float y1 = cy - 0.5f * h;
        float x2 = x1 + w;
        float y2 = y1 + h;
        sh.box[tid][0] = x1; sh.box[tid][1] = y1; sh.box[tid][2] = x2; sh.box[tid][3] = y2;
        sh.box[tid][4] = fmaxf(x2 - x1, 0.0f) * fmaxf(y2 - y1, 0.0f);
        sh.score[tid] = sc;
    }
    __syncthreads();

    // ---- Phase 4: row-per-thread suppression masks (upper triangle, regs only)
    {
        u64 m0 = 0ull, m1 = 0ull, m2 = 0ull, m3 = 0ull;
        if (tid < nk) {
            const float bx0 = sh.box[tid][0], by0 = sh.box[tid][1];
            const float bx1 = sh.box[tid][2], by1 = sh.box[tid][3];
            const float aj  = sh.box[tid][4];
            #pragma unroll
            for (int c = 0; c < 4; ++c) {
                u64 mm = 0ull;
                int klo = tid + 1 > (c << 6) ? tid + 1 : (c << 6);
                int khi = nk < ((c + 1) << 6) ? nk : ((c + 1) << 6);
                for (int k = klo; k < khi; ++k) {
                    float ltx = fmaxf(bx0, sh.box[k][0]);
                    float lty = fmaxf(by0, sh.box[k][1]);
                    float rbx = fminf(bx1, sh.box[k][2]);
                    float rby = fminf(by1, sh.box[k][3]);
                    float wx = fmaxf(rbx - ltx, 0.0f);
                    float wy = fmaxf(rby - lty, 0.0f);
                    float inter = wx * wy;
                    float uni = (aj + sh.box[k][4]) - inter;
                    float iou = inter / fmaxf(uni, 1e-12f);
                    if (iou > NMS_T) mm |= 1ull << (k & 63);
                }
                if (c == 0) m0 = mm; else if (c == 1) m1 = mm;
                else if (c == 2) m2 = mm; else m3 = mm;
            }
        }
        if (tid < TOP_K) {
            sh.sup[tid][0] = m0; sh.sup[tid][1] = m1;
            sh.sup[tid][2] = m2; sh.sup[tid][3] = m3;
        }
    }
    __syncthreads();

    // ---- Phase 5: greedy resolve on wave 0 (64-bit chunks, shfl broadcast)
    if (wv == 0) {
        u64 kws[4];
        #pragma unroll
        for (int w = 0; w < 4; ++w) {
            int rem = nk - (w << 6);
            kws[w] = rem >= 64 ? ~0ull : (rem <= 0 ? 0ull : ((1ull << rem) - 1ull));
        }
        for (int c = 0; c < 4; ++c) {
            int row = (c << 6) + lane;
            u64 myrow = (row < TOP_K) ? sh.sup[row][c] : 0ull;
            u64 kw = kws[c];
            u64 nz = __ballot(myrow != 0ull);
            u64 t = kw & nz;
            while (t) {
                int j = __ffsll(t) - 1;
                u64 rj = __shfl(myrow, j, 64);
                kw &= ~rj;
                t &= ~(1ull << j);
                t &= kw;
            }
            kws[c] = kw;
            for (int w2 = c + 1; w2 < 4; ++w2) {
                u64 contrib = (row < TOP_K && ((kw >> lane) & 1ull)) ? sh.sup[row][w2] : 0ull;
                #pragma unroll
                for (int off = 32; off > 0; off >>= 1) contrib |= __shfl_xor(contrib, off, 64);
                kws[w2] &= ~contrib;
            }
        }
        if (lane == 0) {
            sh.keep[0] = kws[0]; sh.keep[1] = kws[1];
            sh.keep[2] = kws[2]; sh.keep[3] = kws[3];
        }
    }
    __syncthreads();

    // ---- Phase 6: stable compaction of kept rows
    if (tid < nk) {
        int w = tid >> 6, rr = tid & 63;
        u64 kwv = sh.keep[w];
        if ((kwv >> rr) & 1ull) {
            int pos = __popcll(kwv & ((1ull << rr) - 1ull));
            for (int q = 0; q < w; ++q) pos += __popcll(sh.keep[q]);
            float* o = out + (((size_t)img * NUM_CLASSES + cl) * TOP_K + pos) * 5;
            o[0] = sh.score[tid];
            o[1] = sh.box[tid][0];
            o[2] = sh.box[tid][1];
            o[3] = sh.box[tid][2];
            o[4] = sh.box[tid][3];
        }
    }
}

extern "C" void kernel_launch(void* const* d_in, const int* in_sizes, int n_in,
                              void* d_out, int out_size, void* d_ws, size_t ws_size,
                              hipStream_t stream) {
    const float* loc   = (const float*)d_in[0];
    const float* conf  = (const float*)d_in[1];
    const float* prior = (const float*)d_in[2];
    float* out = (float*)d_out;

    hipMemsetAsync(d_out, 0, (size_t)out_size * sizeof(float), stream);

    // ws layout: [0, NTASK*4) counts | [65536, 65536 + NTASK*CAP*8) keys
    const size_t need = 65536 + (size_t)NTASK * CAP * 8;
    const int use_ws = (ws_size >= need) ? 1 : 0;   // constant per session -> deterministic

    u32* counts = (u32*)d_ws;
    u64* keys   = (u64*)((char*)d_ws + 65536);

    if (use_ws) {
        hipMemsetAsync(d_ws, 0, NTASK * sizeof(u32), stream);
        filter_kernel<<<FILTER_BLOCKS, 256, 0, stream>>>((const float4*)conf, counts, keys);
    }
    nms_kernel<<<NTASK, 256, 0, stream>>>(loc, conf, prior,
                                          use_ws ? counts : nullptr,
                                          use_ws ? keys : nullptr,
                                          out, use_ws);
}